// Round 1
// baseline (173.197 us; speedup 1.0000x reference)
//
#include <hip/hip_runtime.h>
#include <hip/hip_bf16.h>

// MoEStage: B=32 T=2048 DM=128 DFE=64 DH=64 DRH=64 E=8 NF=16 NSF=64 TOPK=2
// K0: fold weights (Wf@We1f, Wp@Wr1[128:]) + pre-swizzled bf16 B-tiles in ws
// K1: LN + f32 router (readlane GEMV) + softmax/top2 + gather lists + out-init
// K2: per-expert gathered MFMA bf16 dual-GEMM + gelu + atomic scatter-add

typedef unsigned short u16;
typedef __attribute__((ext_vector_type(8))) short bfrag;    // 8 bf16 (MFMA A/B)
typedef __attribute__((ext_vector_type(8))) u16 u16x8;
typedef __attribute__((ext_vector_type(4))) float facc;     // MFMA C/D

#define NTOK 65536
#define CAP 65536

// ws layout (bytes)
#define OFF_CNT   ((size_t)0)                      // 8 * 4
#define OFF_LTOK  ((size_t)256)                    // 8*65536*4
#define OFF_LGATE (OFF_LTOK + 2097152)
#define OFF_HWS   (OFF_LGATE + 2097152)            // 65536*128*2
#define OFF_W1T   (OFF_HWS + 16777216)             // 8*64*192*2 (swizzled bf16)
#define OFF_W2T   (OFF_W1T + 196608)               // 8*128*64*2 (swizzled bf16)
#define OFF_B1P   (OFF_W2T + 131072)               // 8*64*4
#define OFF_WPR   (OFF_B1P + 2048)                 // 64*64*4
#define OFF_BR1P  (OFF_WPR + 16384)                // 64*4

__device__ __forceinline__ u16 f2bf(float f) {
  union { __hip_bfloat16 h; u16 u; } cv;
  cv.h = __float2bfloat16(f);
  return cv.u;
}
__device__ __forceinline__ float rl(float v, int l) {
  return __int_as_float(__builtin_amdgcn_readlane(__float_as_int(v), l));
}

// ---------------- K0: weight folding + pre-swizzled bf16 tiles ----------------
__global__ __launch_bounds__(256)
void k0_pre(const float* __restrict__ Wp, const float* __restrict__ bp,
            const float* __restrict__ Wr1, const float* __restrict__ br1,
            const float* __restrict__ Wf, const float* __restrict__ bfv,
            const float* __restrict__ We1h, const float* __restrict__ We1f,
            const float* __restrict__ be1, const float* __restrict__ We2,
            float* __restrict__ Wpr, float* __restrict__ br1p,
            u16* __restrict__ w1t, u16* __restrict__ w2t, float* __restrict__ b1p)
{
  int j = blockIdx.x * 256 + threadIdx.x;
  if (j < 4096) {                       // Wpr[i][o] = sum_k Wp[i][k] * Wr1[128+k][o]
    int i = j >> 6, o = j & 63;
    float s = 0.f;
    for (int k = 0; k < 64; ++k) s += Wp[i*64+k] * Wr1[(128+k)*64 + o];
    Wpr[i*64+o] = s;
  } else if (j < 4160) {                // br1p[o] = br1[o] + sum_k bp[k]*Wr1[128+k][o]
    int o = j - 4096;
    float s = br1[o];
    for (int k = 0; k < 64; ++k) s += bp[k] * Wr1[(128+k)*64 + o];
    br1p[o] = s;
  } else if (j < 4160 + 98304) {        // w1t[e][jj][k] (B^T tile, swizzled)
    int idx = j - 4160;
    int e = idx / 12288; int rem = idx % 12288;
    int jj = rem / 192; int k = rem % 192;
    float v = 0.f;
    if (k < 128) v = We1h[(e*128 + k)*64 + jj];
    else if (k < 144) {                 // (Wf @ We1f)[k-128][jj]
      int i = k - 128; float s = 0.f;
      for (int d = 0; d < 64; ++d) s += Wf[(e*16+i)*64 + d] * We1f[(e*64+d)*64 + jj];
      v = s;
    }                                   // k in [144,192): zero pad
    size_t byte = (size_t)(e*64 + jj)*384 + ((2*k) ^ ((jj & 7) << 4));
    *(u16*)((char*)w1t + byte) = f2bf(v);
  } else if (j < 4160 + 98304 + 65536) { // w2t[e][d][k] = We2[e][k][d] (swizzled)
    int idx = j - 4160 - 98304;
    int e = idx / 8192; int rem = idx % 8192;
    int d = rem / 64; int k = rem & 63;
    float v = We2[(e*64 + k)*128 + d];
    size_t byte = (size_t)(e*128 + d)*128 + ((2*k) ^ ((d & 7) << 4));
    *(u16*)((char*)w2t + byte) = f2bf(v);
  } else if (j < 4160 + 98304 + 65536 + 512) { // b1p[e][o] = be1 + bf@We1f
    int idx = j - 4160 - 98304 - 65536;
    int e = idx >> 6, o = idx & 63;
    float s = be1[e*64 + o];
    for (int d = 0; d < 64; ++d) s += bfv[e*64 + d] * We1f[(e*64+d)*64 + o];
    b1p[e*64 + o] = s;
  }
}

// ---------------- K1: LN + router + gather lists ----------------
__device__ __forceinline__ void finalize_token(
    int t, const float lo[8], int lane, const int* __restrict__ seqlen,
    float* __restrict__ outG, float* __restrict__ outP,
    int* lcnt, int (*ltok)[64], float (*lgate)[64])
{
  float mx = lo[0];
  #pragma unroll
  for (int o = 1; o < 8; ++o) mx = fmaxf(mx, lo[o]);
  float ex[8]; float s = 0.f;
  #pragma unroll
  for (int o = 0; o < 8; ++o) { ex[o] = __expf(lo[o] - mx); s += ex[o]; }
  float inv = 1.f / s;
  float p[8];
  #pragma unroll
  for (int o = 0; o < 8; ++o) p[o] = ex[o] * inv;
  float p1 = p[0]; int i1 = 0;
  #pragma unroll
  for (int o = 1; o < 8; ++o) { bool tk = p[o] > p1; p1 = tk ? p[o] : p1; i1 = tk ? o : i1; }
  float p2 = -1.f; int i2 = 0;
  #pragma unroll
  for (int o = 0; o < 8; ++o) { bool tk = (o != i1) && (p[o] > p2); p2 = tk ? p[o] : p2; i2 = tk ? o : i2; }
  int b = t >> 11, ti = t & 2047;
  bool valid = ti < seqlen[b];
  float gden = 1.f / (p1 + p2);
  float g1 = p1 * gden, g2 = p2 * gden;
  float pv = p[0];
  #pragma unroll
  for (int o = 1; o < 8; ++o) pv = (lane == o) ? p[o] : pv;
  if (lane < 8) outP[t*8 + lane] = pv;
  float gv = (lane == i1) ? g1 : ((lane == i2) ? g2 : 0.f);
  if (!valid) gv = 0.f;
  if (lane < 8) outG[t*8 + lane] = gv;
  if (valid && lane == 0) {
    int lp = atomicAdd(&lcnt[i1], 1); ltok[i1][lp] = t; lgate[i1][lp] = g1;
    lp = atomicAdd(&lcnt[i2], 1); ltok[i2][lp] = t; lgate[i2][lp] = g2;
  }
}

__global__ __launch_bounds__(512)
void k1_router(const float* __restrict__ hidden, const float* __restrict__ feat,
               const float* __restrict__ ln_g, const float* __restrict__ ln_b,
               const float* __restrict__ Wr1, const float* __restrict__ Wr2,
               const float* __restrict__ br2, const int* __restrict__ seqlen,
               const int* __restrict__ sidx_g,
               const float* __restrict__ Wpr, const float* __restrict__ br1p,
               float* __restrict__ outN, float* __restrict__ outG, float* __restrict__ outP,
               u16* __restrict__ hws, int* __restrict__ cnt,
               int* __restrict__ listTok, float* __restrict__ listGate)
{
  __shared__ float Wall[192*64];   // [d][j]: rows 0..127 = Wr1[:128], 128..191 = Wpr
  __shared__ float W2t[8*64];      // [o][j]
  __shared__ float sb1[64], sg[128], sb[128], sbr2[8];
  __shared__ int ssidx[64];
  __shared__ int lcnt[8], lbase[8];
  __shared__ int ltok[8][64];
  __shared__ float lgate[8][64];

  int tid = threadIdx.x;
  for (int i = tid; i < 2048; i += 512) ((float4*)Wall)[i] = ((const float4*)Wr1)[i];
  for (int i = tid; i < 1024; i += 512) ((float4*)(Wall + 128*64))[i] = ((const float4*)Wpr)[i];
  if (tid < 512) { int o = tid >> 6, jj = tid & 63; W2t[o*64 + jj] = Wr2[jj*8 + o]; }
  if (tid < 64) { sb1[tid] = br1p[tid]; ssidx[tid] = sidx_g[tid]; }
  if (tid < 128) { sg[tid] = ln_g[tid]; sb[tid] = ln_b[tid]; }
  if (tid < 8) { sbr2[tid] = br2[tid]; lcnt[tid] = 0; }
  __syncthreads();

  int w = tid >> 6, lane = tid & 63;
  int base = blockIdx.x * 64 + w * 8;

  #pragma unroll 1
  for (int it = 0; it < 4; ++it) {
    int tA = base + it*2, tB = tA + 1;
    float xA0 = hidden[tA*128 + lane],      xA1 = hidden[tA*128 + 64 + lane];
    float xB0 = hidden[tB*128 + lane],      xB1 = hidden[tB*128 + 64 + lane];
    outN[tA*128 + lane] = xA0; outN[tA*128 + 64 + lane] = xA1;
    outN[tB*128 + lane] = xB0; outN[tB*128 + 64 + lane] = xB1;
    float sA = xA0 + xA1, sB = xB0 + xB1;
    #pragma unroll
    for (int m = 1; m < 64; m <<= 1) { sA += __shfl_xor(sA, m, 64); sB += __shfl_xor(sB, m, 64); }
    float muA = sA * (1.f/128.f), muB = sB * (1.f/128.f);
    float dA0 = xA0-muA, dA1 = xA1-muA, dB0 = xB0-muB, dB1 = xB1-muB;
    float qA = dA0*dA0 + dA1*dA1, qB = dB0*dB0 + dB1*dB1;
    #pragma unroll
    for (int m = 1; m < 64; m <<= 1) { qA += __shfl_xor(qA, m, 64); qB += __shfl_xor(qB, m, 64); }
    float rsA = rsqrtf(qA*(1.f/128.f) + 1e-5f), rsB = rsqrtf(qB*(1.f/128.f) + 1e-5f);
    float hA0 = dA0*rsA*sg[lane]    + sb[lane],    hA1 = dA1*rsA*sg[64+lane] + sb[64+lane];
    float hB0 = dB0*rsB*sg[lane]    + sb[lane],    hB1 = dB1*rsB*sg[64+lane] + sb[64+lane];
    hws[tA*128 + lane] = f2bf(hA0); hws[tA*128 + 64 + lane] = f2bf(hA1);
    hws[tB*128 + lane] = f2bf(hB0); hws[tB*128 + 64 + lane] = f2bf(hB1);
    float fA = feat[tA*64 + ssidx[lane]], fB = feat[tB*64 + ssidx[lane]];

    float zA = sb1[lane], zB = sb1[lane];
    #pragma unroll 8
    for (int d = 0; d < 64; ++d) {
      float wv = Wall[d*64 + lane];
      zA = fmaf(rl(hA0, d), wv, zA); zB = fmaf(rl(hB0, d), wv, zB);
    }
    #pragma unroll 8
    for (int d = 0; d < 64; ++d) {
      float wv = Wall[(64+d)*64 + lane];
      zA = fmaf(rl(hA1, d), wv, zA); zB = fmaf(rl(hB1, d), wv, zB);
    }
    #pragma unroll 8
    for (int d = 0; d < 64; ++d) {
      float wv = Wall[(128+d)*64 + lane];
      zA = fmaf(rl(fA, d), wv, zA); zB = fmaf(rl(fB, d), wv, zB);
    }
    float rA = fmaxf(zA, 0.f), rB = fmaxf(zB, 0.f);
    float loA[8], loB[8];
    #pragma unroll
    for (int o = 0; o < 8; ++o) { float wv = W2t[o*64 + lane]; loA[o] = rA*wv; loB[o] = rB*wv; }
    #pragma unroll
    for (int o = 0; o < 8; ++o) {
      float vA = loA[o], vB = loB[o];
      #pragma unroll
      for (int m = 1; m < 64; m <<= 1) { vA += __shfl_xor(vA, m, 64); vB += __shfl_xor(vB, m, 64); }
      loA[o] = vA + sbr2[o]; loB[o] = vB + sbr2[o];
    }
    finalize_token(tA, loA, lane, seqlen, outG, outP, lcnt, ltok, lgate);
    finalize_token(tB, loB, lane, seqlen, outG, outP, lcnt, ltok, lgate);
  }
  __syncthreads();
  if (tid < 8) lbase[tid] = atomicAdd(&cnt[tid], lcnt[tid]);
  __syncthreads();
  #pragma unroll 1
  for (int e = 0; e < 8; ++e) {
    int ncnt = lcnt[e];
    if (tid < ncnt) {
      listTok[e*CAP + lbase[e] + tid] = ltok[e][tid];
      listGate[e*CAP + lbase[e] + tid] = lgate[e][tid];
    }
  }
}

// ---------------- K2: gathered expert MFMA dual-GEMM ----------------
__global__ __launch_bounds__(256)
void k2_experts(const float* __restrict__ feat, const u16* __restrict__ hws,
                const u16* __restrict__ w1t, const u16* __restrict__ w2t,
                const float* __restrict__ b1p, const float* __restrict__ be2,
                const float* __restrict__ alphap, const int* __restrict__ eidx_g,
                const int* __restrict__ cnt, const int* __restrict__ listTok,
                const float* __restrict__ listGate, float* __restrict__ outN)
{
  __shared__ u16 Xs[64*192];    // X tile [row][k] swizzled, K padded to 160(+32)
  __shared__ u16 W1s[64*192];   // B^T [out j][k] swizzled
  __shared__ u16 W2s[128*64];   // B^T [out d][k] swizzled
  __shared__ u16 H1s[64*64];    // gelu output [row][j] swizzled
  __shared__ float b1s[64], be2s[128], gts[64];
  __shared__ int toks[64];
  __shared__ int seidx[16];

  int e = blockIdx.x >> 10;
  int seg = blockIdx.x & 1023;
  int n = cnt[e];
  int row0 = seg << 6;
  if (row0 >= n) return;
  int nr = n - row0; if (nr > 64) nr = 64;
  int tid = threadIdx.x;

  if (tid < 64) {
    int tok = 0; float gt = 0.f;
    if (tid < nr) { tok = listTok[e*CAP + row0 + tid]; gt = listGate[e*CAP + row0 + tid]; }
    toks[tid] = tok; gts[tid] = gt;
    b1s[tid] = b1p[e*64 + tid];
  }
  if (tid >= 64 && tid < 192) be2s[tid - 64] = be2[e*128 + tid - 64];
  if (tid < 16) seidx[tid] = eidx_g[e*16 + tid];
  {
    const u16x8* s1 = (const u16x8*)(w1t + e*64*192);
    u16x8* d1 = (u16x8*)W1s;
    for (int i = tid; i < 1536; i += 256) d1[i] = s1[i];
    const u16x8* s2 = (const u16x8*)(w2t + e*128*64);
    u16x8* d2 = (u16x8*)W2s;
    for (int i = tid; i < 1024; i += 256) d2[i] = s2[i];
  }
  __syncthreads();
  // X: h part (cols 0..127)
  for (int c = tid; c < 1024; c += 256) {
    int r = c >> 4, p = c & 15;
    u16x8 v = *(const u16x8*)(hws + toks[r]*128 + p*8);
    *(u16x8*)((char*)Xs + r*384 + ((p*16) ^ ((r & 7) << 4))) = v;
  }
  // X: feat part (cols 128..143) + zero pad (144..159)
  if (tid < 128) {
    int r = tid >> 1, hf = tid & 1;
    int tok = toks[r];
    u16x8 ov;
    #pragma unroll
    for (int q = 0; q < 8; ++q) ov[q] = f2bf(feat[tok*64 + seidx[hf*8 + q]]);
    *(u16x8*)((char*)Xs + r*384 + ((256 + hf*16) ^ ((r & 7) << 4))) = ov;
    u16x8 zv = {0,0,0,0,0,0,0,0};
    *(u16x8*)((char*)Xs + r*384 + ((288 + hf*16) ^ ((r & 7) << 4))) = zv;
  }
  __syncthreads();

  int w = tid >> 6, lane = tid & 63;
  int la = lane & 15, lg = lane >> 4;
  int wm = (w >> 1) * 32, wn = (w & 1) * 32;

  facc acc[2][2];
  #pragma unroll
  for (int a = 0; a < 2; ++a)
    #pragma unroll
    for (int b2 = 0; b2 < 2; ++b2) { facc z = {0.f,0.f,0.f,0.f}; acc[a][b2] = z; }
  #pragma unroll
  for (int kc = 0; kc < 5; ++kc) {
    int kb = kc*64 + lg*16;
    bfrag af[2], bf2[2];
    #pragma unroll
    for (int mi = 0; mi < 2; ++mi) {
      int r = wm + mi*16 + la;
      af[mi] = *(const bfrag*)((const char*)Xs + r*384 + (kb ^ ((r & 7) << 4)));
    }
    #pragma unroll
    for (int ni = 0; ni < 2; ++ni) {
      int r = wn + ni*16 + la;
      bf2[ni] = *(const bfrag*)((const char*)W1s + r*384 + (kb ^ ((r & 7) << 4)));
    }
    #pragma unroll
    for (int mi = 0; mi < 2; ++mi)
      #pragma unroll
      for (int ni = 0; ni < 2; ++ni)
        acc[mi][ni] = __builtin_amdgcn_mfma_f32_16x16x32_bf16(af[mi], bf2[ni], acc[mi][ni], 0, 0, 0);
  }
  // bias + exact gelu -> H1s
  #pragma unroll
  for (int mi = 0; mi < 2; ++mi)
    #pragma unroll
    for (int ni = 0; ni < 2; ++ni)
      #pragma unroll
      for (int rg = 0; rg < 4; ++rg) {
        int r = wm + mi*16 + lg*4 + rg;
        int c = wn + ni*16 + la;
        float z = acc[mi][ni][rg] + b1s[c];
        float gl = 0.5f * z * (1.f + erff(z * 0.70710678118f));
        *(u16*)((char*)H1s + r*128 + ((2*c) ^ ((r & 7) << 4))) = f2bf(gl);
      }
  __syncthreads();

  facc acc2[2][4];
  #pragma unroll
  for (int a = 0; a < 2; ++a)
    #pragma unroll
    for (int b2 = 0; b2 < 4; ++b2) { facc z = {0.f,0.f,0.f,0.f}; acc2[a][b2] = z; }
  int wn2 = (w & 1) * 64;
  #pragma unroll
  for (int kc = 0; kc < 2; ++kc) {
    int kb = kc*64 + lg*16;
    bfrag af[2], bf2[4];
    #pragma unroll
    for (int mi = 0; mi < 2; ++mi) {
      int r = wm + mi*16 + la;
      af[mi] = *(const bfrag*)((const char*)H1s + r*128 + (kb ^ ((r & 7) << 4)));
    }
    #pragma unroll
    for (int ni = 0; ni < 4; ++ni) {
      int r = wn2 + ni*16 + la;
      bf2[ni] = *(const bfrag*)((const char*)W2s + r*128 + (kb ^ ((r & 7) << 4)));
    }
    #pragma unroll
    for (int mi = 0; mi < 2; ++mi)
      #pragma unroll
      for (int ni = 0; ni < 4; ++ni)
        acc2[mi][ni] = __builtin_amdgcn_mfma_f32_16x16x32_bf16(af[mi], bf2[ni], acc2[mi][ni], 0, 0, 0);
  }
  float alpha = alphap[0];
  #pragma unroll
  for (int mi = 0; mi < 2; ++mi)
    #pragma unroll
    for (int ni = 0; ni < 4; ++ni)
      #pragma unroll
      for (int rg = 0; rg < 4; ++rg) {
        int r = wm + mi*16 + lg*4 + rg;
        int c = wn2 + ni*16 + la;
        float gt = gts[r];
        if (gt != 0.f) {
          float v = acc2[mi][ni][rg] + be2s[c];
          atomicAdd(outN + toks[r]*128 + c, alpha * gt * v);
        }
      }
}

// ---------------- launch ----------------
extern "C" void kernel_launch(void* const* d_in, const int* in_sizes, int n_in,
                              void* d_out, int out_size, void* d_ws, size_t ws_size,
                              hipStream_t stream) {
  const float* hidden = (const float*)d_in[0];
  const float* feat   = (const float*)d_in[1];
  const float* ln_g   = (const float*)d_in[2];
  const float* ln_b   = (const float*)d_in[3];
  const float* Wp     = (const float*)d_in[4];
  const float* bp     = (const float*)d_in[5];
  const float* Wr1    = (const float*)d_in[6];
  const float* br1    = (const float*)d_in[7];
  const float* Wr2    = (const float*)d_in[8];
  const float* br2    = (const float*)d_in[9];
  const float* Wf     = (const float*)d_in[10];
  const float* bfv    = (const float*)d_in[11];
  const float* We1h   = (const float*)d_in[12];
  const float* We1f   = (const float*)d_in[13];
  const float* be1    = (const float*)d_in[14];
  const float* We2    = (const float*)d_in[15];
  const float* be2    = (const float*)d_in[16];
  const float* alpha  = (const float*)d_in[17];
  const int* seqlen   = (const int*)d_in[18];
  const int* eidx     = (const int*)d_in[19];
  const int* sidx     = (const int*)d_in[20];

  char* ws = (char*)d_ws;
  int*   cnt      = (int*)(ws + OFF_CNT);
  int*   listTok  = (int*)(ws + OFF_LTOK);
  float* listGate = (float*)(ws + OFF_LGATE);
  u16*   hws      = (u16*)(ws + OFF_HWS);
  u16*   w1t      = (u16*)(ws + OFF_W1T);
  u16*   w2t      = (u16*)(ws + OFF_W2T);
  float* b1p      = (float*)(ws + OFF_B1P);
  float* Wpr      = (float*)(ws + OFF_WPR);
  float* br1p     = (float*)(ws + OFF_BR1P);

  float* outN = (float*)d_out;
  float* outG = outN + (size_t)NTOK * 128;
  float* outP = outG + (size_t)NTOK * 8;

  hipMemsetAsync(ws + OFF_CNT, 0, 256, stream);
  k0_pre<<<659, 256, 0, stream>>>(Wp, bp, Wr1, br1, Wf, bfv, We1h, We1f, be1, We2,
                                  Wpr, br1p, w1t, w2t, b1p);
  k1_router<<<1024, 512, 0, stream>>>(hidden, feat, ln_g, ln_b, Wr1, Wr2, br2, seqlen,
                                      sidx, Wpr, br1p, outN, outG, outP, hws, cnt,
                                      listTok, listGate);
  k2_experts<<<8192, 256, 0, stream>>>(feat, hws, w1t, w2t, b1p, be2, alpha, eidx,
                                       cnt, listTok, listGate, outN);
}

// Round 2
// 111.209 us; speedup vs baseline: 1.5574x; 1.5574x over previous
//
#include <hip/hip_runtime.h>
#include <hip/hip_bf16.h>

// MoEStage: B=32 T=2048 DM=128 DFE=64 DH=64 DRH=64 E=8 NF=16 NSF=64 TOPK=2
// K0: fold weights (Wf@We1f, Wp@Wr1[128:]) + pre-swizzled bf16 B-tiles in ws
// K1: LN + tiled f32 router GEMM (selection-critical => f32) + top2 + lists
// K2: per-expert gathered MFMA bf16 dual-GEMM + gelu + atomic scatter-add

typedef unsigned short u16;
typedef __attribute__((ext_vector_type(8))) short bfrag;    // 8 bf16 (MFMA A/B)
typedef __attribute__((ext_vector_type(8))) u16 u16x8;
typedef __attribute__((ext_vector_type(4))) float facc;     // MFMA C/D
typedef __attribute__((ext_vector_type(4))) float f32x4;

#define NTOK 65536
#define CAP 65536

// ws layout (bytes)
#define OFF_CNT   ((size_t)0)                      // 8 * 4
#define OFF_LTOK  ((size_t)256)                    // 8*65536*4
#define OFF_LGATE (OFF_LTOK + 2097152)
#define OFF_HWS   (OFF_LGATE + 2097152)            // 65536*128*2
#define OFF_W1T   (OFF_HWS + 16777216)             // 8*64*192*2 (swizzled bf16)
#define OFF_W2T   (OFF_W1T + 196608)               // 8*128*64*2 (swizzled bf16)
#define OFF_B1P   (OFF_W2T + 131072)               // 8*64*4
#define OFF_WPR   (OFF_B1P + 2048)                 // 64*64*4
#define OFF_BR1P  (OFF_WPR + 16384)                // 64*4

__device__ __forceinline__ u16 f2bf(float f) {
  union { __hip_bfloat16 h; u16 u; } cv;
  cv.h = __float2bfloat16(f);
  return cv.u;
}

// ---------------- K0: weight folding + pre-swizzled bf16 tiles ----------------
__global__ __launch_bounds__(256)
void k0_pre(const float* __restrict__ Wp, const float* __restrict__ bp,
            const float* __restrict__ Wr1, const float* __restrict__ br1,
            const float* __restrict__ Wf, const float* __restrict__ bfv,
            const float* __restrict__ We1h, const float* __restrict__ We1f,
            const float* __restrict__ be1, const float* __restrict__ We2,
            float* __restrict__ Wpr, float* __restrict__ br1p,
            u16* __restrict__ w1t, u16* __restrict__ w2t, float* __restrict__ b1p)
{
  int j = blockIdx.x * 256 + threadIdx.x;
  if (j < 4096) {                       // Wpr[i][o] = sum_k Wp[i][k] * Wr1[128+k][o]
    int i = j >> 6, o = j & 63;
    float s = 0.f;
    for (int k = 0; k < 64; ++k) s += Wp[i*64+k] * Wr1[(128+k)*64 + o];
    Wpr[i*64+o] = s;
  } else if (j < 4160) {                // br1p[o] = br1[o] + sum_k bp[k]*Wr1[128+k][o]
    int o = j - 4096;
    float s = br1[o];
    for (int k = 0; k < 64; ++k) s += bp[k] * Wr1[(128+k)*64 + o];
    br1p[o] = s;
  } else if (j < 4160 + 98304) {        // w1t[e][jj][k] (B^T tile, swizzled)
    int idx = j - 4160;
    int e = idx / 12288; int rem = idx % 12288;
    int jj = rem / 192; int k = rem % 192;
    float v = 0.f;
    if (k < 128) v = We1h[(e*128 + k)*64 + jj];
    else if (k < 144) {                 // (Wf @ We1f)[k-128][jj]
      int i = k - 128; float s = 0.f;
      for (int d = 0; d < 64; ++d) s += Wf[(e*16+i)*64 + d] * We1f[(e*64+d)*64 + jj];
      v = s;
    }                                   // k in [144,192): zero pad
    size_t byte = (size_t)(e*64 + jj)*384 + ((2*k) ^ ((jj & 7) << 4));
    *(u16*)((char*)w1t + byte) = f2bf(v);
  } else if (j < 4160 + 98304 + 65536) { // w2t[e][d][k] = We2[e][k][d] (swizzled)
    int idx = j - 4160 - 98304;
    int e = idx / 8192; int rem = idx % 8192;
    int d = rem / 64; int k = rem & 63;
    float v = We2[(e*64 + k)*128 + d];
    size_t byte = (size_t)(e*128 + d)*128 + ((2*k) ^ ((d & 7) << 4));
    *(u16*)((char*)w2t + byte) = f2bf(v);
  } else if (j < 4160 + 98304 + 65536 + 512) { // b1p[e][o] = be1 + bf@We1f
    int idx = j - 4160 - 98304 - 65536;
    int e = idx >> 6, o = idx & 63;
    float s = be1[e*64 + o];
    for (int d = 0; d < 64; ++d) s += bfv[e*64 + d] * We1f[(e*64+d)*64 + o];
    b1p[e*64 + o] = s;
  }
}

// ---------------- K1: LN + tiled f32 router GEMM + top2 + lists ----------------
// block = 512 threads = 8 waves, 128 tokens/block (16/wave), grid = 512.
// GEMM: Z[128 tok][64 out] = rin[128][192] @ Wr1cat[192][64], K in 3 chunks of 64.
// Wave layout: lane&15 -> out-group (4 outs), lane>>4 -> token subgroup (4 toks).
__global__ __launch_bounds__(512)
void k1_router(const float* __restrict__ hidden, const float* __restrict__ feat,
               const float* __restrict__ ln_g, const float* __restrict__ ln_b,
               const float* __restrict__ Wr1, const float* __restrict__ Wr2,
               const float* __restrict__ br2, const int* __restrict__ seqlen,
               const int* __restrict__ sidx_g,
               const float* __restrict__ Wpr, const float* __restrict__ br1p,
               float* __restrict__ outN, float* __restrict__ outG, float* __restrict__ outP,
               u16* __restrict__ hws, int* __restrict__ cnt,
               int* __restrict__ listTok, float* __restrict__ listGate)
{
  __shared__ float At[64*128];     // [k][tok] f32, XOR-swizzled (32 KB)
  __shared__ float Wc[64*64];      // [k][out] f32 chunk (16 KB)
  __shared__ float sW2[64*8];      // Wr2 [out][e]
  __shared__ float sb1[64], sg[128], sb[128], sbr2[8];
  __shared__ int ssidx[64];
  __shared__ int lcnt[8], lbase[8];
  __shared__ int ltok[8][128];
  __shared__ float lgate[8][128];

  int tid = threadIdx.x;
  int w = tid >> 6, lane = tid & 63;

  if (tid < 512) sW2[tid] = Wr2[tid];
  if (tid < 64) { sb1[tid] = br1p[tid]; ssidx[tid] = sidx_g[tid]; }
  if (tid >= 64 && tid < 192) { int i = tid - 64; sg[i] = ln_g[i]; }
  if (tid >= 192 && tid < 320) { int i = tid - 192; sb[i] = ln_b[i]; }
  if (tid >= 320 && tid < 328) { sbr2[tid-320] = br2[tid-320]; }
  if (tid >= 328 && tid < 336) { lcnt[tid-328] = 0; }
  __syncthreads();

  int tbase = blockIdx.x * 128 + w * 16;

  // ---- Phase A: LN, keep h0/h1/feat in regs, write outN + hws ----
  float h0v[16], h1v[16], fv[16];
  #pragma unroll
  for (int p = 0; p < 8; ++p) {
    int tA = tbase + 2*p, tB = tA + 1;
    float xA0 = hidden[tA*128 + lane],      xA1 = hidden[tA*128 + 64 + lane];
    float xB0 = hidden[tB*128 + lane],      xB1 = hidden[tB*128 + 64 + lane];
    fv[2*p]   = feat[tA*64 + ssidx[lane]];
    fv[2*p+1] = feat[tB*64 + ssidx[lane]];
    outN[tA*128 + lane] = xA0; outN[tA*128 + 64 + lane] = xA1;
    outN[tB*128 + lane] = xB0; outN[tB*128 + 64 + lane] = xB1;
    float sA = xA0 + xA1, sB = xB0 + xB1;
    #pragma unroll
    for (int m = 1; m < 64; m <<= 1) { sA += __shfl_xor(sA, m, 64); sB += __shfl_xor(sB, m, 64); }
    float muA = sA * (1.f/128.f), muB = sB * (1.f/128.f);
    float dA0 = xA0-muA, dA1 = xA1-muA, dB0 = xB0-muB, dB1 = xB1-muB;
    float qA = dA0*dA0 + dA1*dA1, qB = dB0*dB0 + dB1*dB1;
    #pragma unroll
    for (int m = 1; m < 64; m <<= 1) { qA += __shfl_xor(qA, m, 64); qB += __shfl_xor(qB, m, 64); }
    float rsA = rsqrtf(qA*(1.f/128.f) + 1e-5f), rsB = rsqrtf(qB*(1.f/128.f) + 1e-5f);
    float hA0 = dA0*rsA*sg[lane]    + sb[lane],    hA1 = dA1*rsA*sg[64+lane] + sb[64+lane];
    float hB0 = dB0*rsB*sg[lane]    + sb[lane],    hB1 = dB1*rsB*sg[64+lane] + sb[64+lane];
    hws[tA*128 + lane] = f2bf(hA0); hws[tA*128 + 64 + lane] = f2bf(hA1);
    hws[tB*128 + lane] = f2bf(hB0); hws[tB*128 + 64 + lane] = f2bf(hB1);
    h0v[2*p] = hA0; h1v[2*p] = hA1; h0v[2*p+1] = hB0; h1v[2*p+1] = hB1;
  }

  // ---- Phase B: 3 K-chunks of f32 GEMM ----
  float acc[4][4];
  #pragma unroll
  for (int i = 0; i < 4; ++i)
    #pragma unroll
    for (int q = 0; q < 4; ++q) acc[i][q] = 0.f;

  int tb = w*4 + (lane >> 4);          // token-block (4 tokens) this lane reads
  int ob = (lane & 15) * 4;            // first output col this lane owns

  #pragma unroll 1
  for (int c = 0; c < 3; ++c) {
    __syncthreads();                    // previous chunk's reads done
    const float* wsrc = (c == 0) ? Wr1 : (c == 1) ? (Wr1 + 64*64) : Wpr;
    for (int i = tid; i < 1024; i += 512) ((f32x4*)Wc)[i] = ((const f32x4*)wsrc)[i];
    // write A^T chunk: row k = lane, 16 tokens of this wave, swizzled
    #pragma unroll
    for (int tk = 0; tk < 16; ++tk) {
      int tl = w*16 + tk;
      float v = (c == 0) ? h0v[tk] : (c == 1) ? h1v[tk] : fv[tk];
      int byte = (lane << 9) + (((((tl >> 2) ^ (lane & 15))) << 4) | ((tl & 3) << 2));
      *(float*)((char*)At + byte) = v;
    }
    __syncthreads();
    #pragma unroll 4
    for (int k = 0; k < 64; ++k) {
      f32x4 a4 = *(const f32x4*)((const char*)At + (k << 9) + ((tb ^ (k & 15)) << 4));
      f32x4 b4 = *(const f32x4*)(Wc + k*64 + ob);
      #pragma unroll
      for (int i = 0; i < 4; ++i)
        #pragma unroll
        for (int q = 0; q < 4; ++q)
          acc[i][q] = fmaf(a4[i], b4[q], acc[i][q]);
    }
  }

  // ---- Phase C: logits, softmax, top2, lists ----
  float w2r[4][8];
  #pragma unroll
  for (int q = 0; q < 4; ++q)
    #pragma unroll
    for (int e = 0; e < 8; ++e) w2r[q][e] = sW2[(ob + q)*8 + e];
  float b1r[4];
  #pragma unroll
  for (int q = 0; q < 4; ++q) b1r[q] = sb1[ob + q];

  int j = lane & 15;
  #pragma unroll 1
  for (int ti = 0; ti < 4; ++ti) {
    float lo[8];
    #pragma unroll
    for (int e = 0; e < 8; ++e) lo[e] = 0.f;
    #pragma unroll
    for (int q = 0; q < 4; ++q) {
      float z = fmaxf(acc[ti][q] + b1r[q], 0.f);
      #pragma unroll
      for (int e = 0; e < 8; ++e) lo[e] = fmaf(z, w2r[q][e], lo[e]);
    }
    #pragma unroll
    for (int m = 1; m < 16; m <<= 1) {
      #pragma unroll
      for (int e = 0; e < 8; ++e) lo[e] += __shfl_xor(lo[e], m, 64);
    }
    #pragma unroll
    for (int e = 0; e < 8; ++e) lo[e] += sbr2[e];

    int t = tbase + (lane >> 4)*4 + ti;
    float mx = lo[0];
    #pragma unroll
    for (int e = 1; e < 8; ++e) mx = fmaxf(mx, lo[e]);
    float ex[8]; float s = 0.f;
    #pragma unroll
    for (int e = 0; e < 8; ++e) { ex[e] = __expf(lo[e] - mx); s += ex[e]; }
    float inv = 1.f / s;
    float p[8];
    #pragma unroll
    for (int e = 0; e < 8; ++e) p[e] = ex[e] * inv;
    float p1 = p[0]; int i1 = 0;
    #pragma unroll
    for (int e = 1; e < 8; ++e) { bool tk2 = p[e] > p1; p1 = tk2 ? p[e] : p1; i1 = tk2 ? e : i1; }
    float p2 = -1.f; int i2 = 0;
    #pragma unroll
    for (int e = 0; e < 8; ++e) { bool tk2 = (e != i1) && (p[e] > p2); p2 = tk2 ? p[e] : p2; i2 = tk2 ? e : i2; }
    int bb = t >> 11, tt = t & 2047;
    bool valid = tt < seqlen[bb];
    float gden = 1.f / (p1 + p2);
    float g1 = p1 * gden, g2 = p2 * gden;
    float pv = p[0];
    #pragma unroll
    for (int e = 1; e < 8; ++e) pv = (j == e) ? p[e] : pv;
    if (j < 8) outP[t*8 + j] = pv;
    float gv = (j == i1) ? g1 : ((j == i2) ? g2 : 0.f);
    if (!valid) gv = 0.f;
    if (j < 8) outG[t*8 + j] = gv;
    if (valid && j == 0) {
      int lp = atomicAdd(&lcnt[i1], 1); ltok[i1][lp] = t; lgate[i1][lp] = g1;
      lp = atomicAdd(&lcnt[i2], 1); ltok[i2][lp] = t; lgate[i2][lp] = g2;
    }
  }

  __syncthreads();
  if (tid < 8) lbase[tid] = atomicAdd(&cnt[tid], lcnt[tid]);
  __syncthreads();
  #pragma unroll 1
  for (int e = 0; e < 8; ++e) {
    int ncnt = lcnt[e];
    if (tid < ncnt) {
      listTok[e*CAP + lbase[e] + tid] = ltok[e][tid];
      listGate[e*CAP + lbase[e] + tid] = lgate[e][tid];
    }
  }
}

// ---------------- K2: gathered expert MFMA dual-GEMM ----------------
__global__ __launch_bounds__(256)
void k2_experts(const float* __restrict__ feat, const u16* __restrict__ hws,
                const u16* __restrict__ w1t, const u16* __restrict__ w2t,
                const float* __restrict__ b1p, const float* __restrict__ be2,
                const float* __restrict__ alphap, const int* __restrict__ eidx_g,
                const int* __restrict__ cnt, const int* __restrict__ listTok,
                const float* __restrict__ listGate, float* __restrict__ outN)
{
  __shared__ u16 Xs[64*192];    // X tile [row][k] swizzled, K padded to 160(+32)
  __shared__ u16 W1s[64*192];   // B^T [out j][k] swizzled
  __shared__ u16 W2s[128*64];   // B^T [out d][k] swizzled
  __shared__ u16 H1s[64*64];    // gelu output [row][j] swizzled
  __shared__ float b1s[64], be2s[128], gts[64];
  __shared__ int toks[64];
  __shared__ int seidx[16];

  int e = blockIdx.x >> 10;
  int seg = blockIdx.x & 1023;
  int n = cnt[e];
  int row0 = seg << 6;
  if (row0 >= n) return;
  int nr = n - row0; if (nr > 64) nr = 64;
  int tid = threadIdx.x;

  if (tid < 64) {
    int tok = 0; float gt = 0.f;
    if (tid < nr) { tok = listTok[e*CAP + row0 + tid]; gt = listGate[e*CAP + row0 + tid]; }
    toks[tid] = tok; gts[tid] = gt;
    b1s[tid] = b1p[e*64 + tid];
  }
  if (tid >= 64 && tid < 192) be2s[tid - 64] = be2[e*128 + tid - 64];
  if (tid < 16) seidx[tid] = eidx_g[e*16 + tid];
  {
    const u16x8* s1 = (const u16x8*)(w1t + e*64*192);
    u16x8* d1 = (u16x8*)W1s;
    for (int i = tid; i < 1536; i += 256) d1[i] = s1[i];
    const u16x8* s2 = (const u16x8*)(w2t + e*128*64);
    u16x8* d2 = (u16x8*)W2s;
    for (int i = tid; i < 1024; i += 256) d2[i] = s2[i];
  }
  __syncthreads();
  // X: h part (cols 0..127)
  for (int c = tid; c < 1024; c += 256) {
    int r = c >> 4, p = c & 15;
    u16x8 v = *(const u16x8*)(hws + toks[r]*128 + p*8);
    *(u16x8*)((char*)Xs + r*384 + ((p*16) ^ ((r & 7) << 4))) = v;
  }
  // X: feat part (cols 128..143) + zero pad (144..159)
  if (tid < 128) {
    int r = tid >> 1, hf = tid & 1;
    int tok = toks[r];
    u16x8 ov;
    #pragma unroll
    for (int q = 0; q < 8; ++q) ov[q] = f2bf(feat[tok*64 + seidx[hf*8 + q]]);
    *(u16x8*)((char*)Xs + r*384 + ((256 + hf*16) ^ ((r & 7) << 4))) = ov;
    u16x8 zv = {0,0,0,0,0,0,0,0};
    *(u16x8*)((char*)Xs + r*384 + ((288 + hf*16) ^ ((r & 7) << 4))) = zv;
  }
  __syncthreads();

  int w = tid >> 6, lane = tid & 63;
  int la = lane & 15, lg = lane >> 4;
  int wm = (w >> 1) * 32, wn = (w & 1) * 32;

  facc acc[2][2];
  #pragma unroll
  for (int a = 0; a < 2; ++a)
    #pragma unroll
    for (int b2 = 0; b2 < 2; ++b2) { facc z = {0.f,0.f,0.f,0.f}; acc[a][b2] = z; }
  #pragma unroll
  for (int kc = 0; kc < 5; ++kc) {
    int kb = kc*64 + lg*16;
    bfrag af[2], bf2[2];
    #pragma unroll
    for (int mi = 0; mi < 2; ++mi) {
      int r = wm + mi*16 + la;
      af[mi] = *(const bfrag*)((const char*)Xs + r*384 + (kb ^ ((r & 7) << 4)));
    }
    #pragma unroll
    for (int ni = 0; ni < 2; ++ni) {
      int r = wn + ni*16 + la;
      bf2[ni] = *(const bfrag*)((const char*)W1s + r*384 + (kb ^ ((r & 7) << 4)));
    }
    #pragma unroll
    for (int mi = 0; mi < 2; ++mi)
      #pragma unroll
      for (int ni = 0; ni < 2; ++ni)
        acc[mi][ni] = __builtin_amdgcn_mfma_f32_16x16x32_bf16(af[mi], bf2[ni], acc[mi][ni], 0, 0, 0);
  }
  // bias + exact gelu -> H1s
  #pragma unroll
  for (int mi = 0; mi < 2; ++mi)
    #pragma unroll
    for (int ni = 0; ni < 2; ++ni)
      #pragma unroll
      for (int rg = 0; rg < 4; ++rg) {
        int r = wm + mi*16 + lg*4 + rg;
        int c = wn + ni*16 + la;
        float z = acc[mi][ni][rg] + b1s[c];
        float gl = 0.5f * z * (1.f + erff(z * 0.70710678118f));
        *(u16*)((char*)H1s + r*128 + ((2*c) ^ ((r & 7) << 4))) = f2bf(gl);
      }
  __syncthreads();

  facc acc2[2][4];
  #pragma unroll
  for (int a = 0; a < 2; ++a)
    #pragma unroll
    for (int b2 = 0; b2 < 4; ++b2) { facc z = {0.f,0.f,0.f,0.f}; acc2[a][b2] = z; }
  int wn2 = (w & 1) * 64;
  #pragma unroll
  for (int kc = 0; kc < 2; ++kc) {
    int kb = kc*64 + lg*16;
    bfrag af[2], bf2[4];
    #pragma unroll
    for (int mi = 0; mi < 2; ++mi) {
      int r = wm + mi*16 + la;
      af[mi] = *(const bfrag*)((const char*)H1s + r*128 + (kb ^ ((r & 7) << 4)));
    }
    #pragma unroll
    for (int ni = 0; ni < 4; ++ni) {
      int r = wn2 + ni*16 + la;
      bf2[ni] = *(const bfrag*)((const char*)W2s + r*128 + (kb ^ ((r & 7) << 4)));
    }
    #pragma unroll
    for (int mi = 0; mi < 2; ++mi)
      #pragma unroll
      for (int ni = 0; ni < 4; ++ni)
        acc2[mi][ni] = __builtin_amdgcn_mfma_f32_16x16x32_bf16(af[mi], bf2[ni], acc2[mi][ni], 0, 0, 0);
  }
  float alpha = alphap[0];
  #pragma unroll
  for (int mi = 0; mi < 2; ++mi)
    #pragma unroll
    for (int ni = 0; ni < 4; ++ni)
      #pragma unroll
      for (int rg = 0; rg < 4; ++rg) {
        int r = wm + mi*16 + lg*4 + rg;
        int c = wn2 + ni*16 + la;
        float gt = gts[r];
        if (gt != 0.f) {
          float v = acc2[mi][ni][rg] + be2s[c];
          atomicAdd(outN + toks[r]*128 + c, alpha * gt * v);
        }
      }
}

// ---------------- launch ----------------
extern "C" void kernel_launch(void* const* d_in, const int* in_sizes, int n_in,
                              void* d_out, int out_size, void* d_ws, size_t ws_size,
                              hipStream_t stream) {
  const float* hidden = (const float*)d_in[0];
  const float* feat   = (const float*)d_in[1];
  const float* ln_g   = (const float*)d_in[2];
  const float* ln_b   = (const float*)d_in[3];
  const float* Wp     = (const float*)d_in[4];
  const float* bp     = (const float*)d_in[5];
  const float* Wr1    = (const float*)d_in[6];
  const float* br1    = (const float*)d_in[7];
  const float* Wr2    = (const float*)d_in[8];
  const float* br2    = (const float*)d_in[9];
  const float* Wf     = (const float*)d_in[10];
  const float* bfv    = (const float*)d_in[11];
  const float* We1h   = (const float*)d_in[12];
  const float* We1f   = (const float*)d_in[13];
  const float* be1    = (const float*)d_in[14];
  const float* We2    = (const float*)d_in[15];
  const float* be2    = (const float*)d_in[16];
  const float* alpha  = (const float*)d_in[17];
  const int* seqlen   = (const int*)d_in[18];
  const int* eidx     = (const int*)d_in[19];
  const int* sidx     = (const int*)d_in[20];

  char* ws = (char*)d_ws;
  int*   cnt      = (int*)(ws + OFF_CNT);
  int*   listTok  = (int*)(ws + OFF_LTOK);
  float* listGate = (float*)(ws + OFF_LGATE);
  u16*   hws      = (u16*)(ws + OFF_HWS);
  u16*   w1t      = (u16*)(ws + OFF_W1T);
  u16*   w2t      = (u16*)(ws + OFF_W2T);
  float* b1p      = (float*)(ws + OFF_B1P);
  float* Wpr      = (float*)(ws + OFF_WPR);
  float* br1p     = (float*)(ws + OFF_BR1P);

  float* outN = (float*)d_out;
  float* outG = outN + (size_t)NTOK * 128;
  float* outP = outG + (size_t)NTOK * 8;

  hipMemsetAsync(ws + OFF_CNT, 0, 256, stream);
  k0_pre<<<659, 256, 0, stream>>>(Wp, bp, Wr1, br1, Wf, bfv, We1h, We1f, be1, We2,
                                  Wpr, br1p, w1t, w2t, b1p);
  k1_router<<<512, 512, 0, stream>>>(hidden, feat, ln_g, ln_b, Wr1, Wr2, br2, seqlen,
                                     sidx, Wpr, br1p, outN, outG, outP, hws, cnt,
                                     listTok, listGate);
  k2_experts<<<8192, 256, 0, stream>>>(feat, hws, w1t, w2t, b1p, be2, alpha, eidx,
                                       cnt, listTok, listGate, outN);
}